// Round 5
// baseline (222.026 us; speedup 1.0000x reference)
//
#include <hip/hip_runtime.h>

#define N 512
#define D 512
#define TILE 64        // pair tile: 64x64 per block, 4x4 per thread
#define DC 32          // d-chunk staged in LDS
#define PITCH 36       // 36%32=4 -> worst 2-way bank alias on row-stride-1 reads; 16B aligned
#define NT 8           // N/TILE
#define NTILES 36      // NT*(NT+1)/2 upper-triangular tiles
#define NSLICE 16      // D/DC, each slice atomically accumulates into the single slab

__device__ __forceinline__ void sl1(float& acc, float x, float y) {
    // 2*SmoothL1(d) = m*(2|d|-m), m=min(|d|,1); 0.5 applied in epilogue.
    // abs/neg fold into VOP3 input modifiers: sub, min(abs), fma(abs,neg), fma = 4 VALU
    float d  = x - y;
    float ad = fabsf(d);
    float m  = fminf(ad, 1.0f);
    acc = fmaf(m, fmaf(2.0f, ad, -m), acc);
}

// ws layout (all in the single memset-zeroed zone):
//   Pp[2][N*N] f32 slab (2 MB) -- atomic-accumulated; only i<=j entries ever touched
//   sums[2], fin, cnt          -- scalars
#define ZONE_FLOATS (2 * N * N + 4)

__global__ __launch_bounds__(256, 4) void pair_sums_kernel(
    const float* __restrict__ Tm, const float* __restrict__ Sm,
    float* __restrict__ Pp, float* __restrict__ sums)
{
    const int mat = blockIdx.z;
    const int sl  = blockIdx.y;
    const float* __restrict__ X = mat ? Sm : Tm;
    float* __restrict__ Pm = Pp + (size_t)mat * (N * N);

    // triangular tile decode -> (ti, tj), ti <= tj
    int rem = blockIdx.x, ti = 0;
    while (rem >= NT - ti) { rem -= NT - ti; ++ti; }
    const int tj = ti + rem;
    const int i0 = ti * TILE, j0 = tj * TILE;
    const int d0 = sl * DC;

    __shared__ float Xi[TILE][PITCH];
    __shared__ float Xj[TILE][PITCH];

    const int t  = threadIdx.x;
    const int tx = t & 15;
    const int ty = t >> 4;

    // stage 2 x 64 rows x 32 floats (per array: 512 float4, 2 per thread)
    #pragma unroll
    for (int kk = 0; kk < 2; ++kk) {
        int idx = t + kk * 256;
        int row = idx >> 3;              // 8 float4 per row
        int c4  = (idx & 7) * 4;
        *(float4*)&Xi[row][c4] = *(const float4*)&X[(size_t)(i0 + row) * D + d0 + c4];
        *(float4*)&Xj[row][c4] = *(const float4*)&X[(size_t)(j0 + row) * D + d0 + c4];
    }
    __syncthreads();

    float acc[4][4];
    #pragma unroll
    for (int m = 0; m < 4; ++m)
        #pragma unroll
        for (int n = 0; n < 4; ++n) acc[m][n] = 0.f;

    #pragma unroll
    for (int d4 = 0; d4 < DC / 4; ++d4) {
        float4 p[4], q[4];
        #pragma unroll
        for (int m = 0; m < 4; ++m) p[m] = *(const float4*)&Xi[ty + 16 * m][d4 * 4];
        #pragma unroll
        for (int n = 0; n < 4; ++n) q[n] = *(const float4*)&Xj[tx + 16 * n][d4 * 4];
        #pragma unroll
        for (int m = 0; m < 4; ++m)
            #pragma unroll
            for (int n = 0; n < 4; ++n) {
                sl1(acc[m][n], p[m].x, q[n].x);
                sl1(acc[m][n], p[m].y, q[n].y);
                sl1(acc[m][n], p[m].z, q[n].z);
                sl1(acc[m][n], p[m].w, q[n].w);
            }
    }

    // accumulate into the single slab; on diagonal tiles keep only global i<=j
    const bool diag = (ti == tj);
    float bs = 0.f;
    #pragma unroll
    for (int m = 0; m < 4; ++m)
        #pragma unroll
        for (int n = 0; n < 4; ++n) {
            const int li = ty + 16 * m, lj = tx + 16 * n;
            const float s = 0.5f * acc[m][n];
            if (!diag || (li <= lj)) {
                atomicAdd(&Pm[(i0 + li) * N + (j0 + lj)], s);
                bs += s;
            }
        }

    // block sum of Sum_{i<j} -> one atomic per block (diag pairs contribute 0 anyway)
    #pragma unroll
    for (int off = 32; off > 0; off >>= 1) bs += __shfl_down(bs, off, 64);
    __shared__ float wpart[4];
    if ((t & 63) == 0) wpart[t >> 6] = bs;
    __syncthreads();
    if (t == 0) atomicAdd(&sums[mat], wpart[0] + wpart[1] + wpart[2] + wpart[3]);
}

__global__ __launch_bounds__(256) void final_kernel(
    const float* __restrict__ Pp, float* __restrict__ sums, float* __restrict__ out)
{
    float* fin = sums + 2;
    unsigned int* cnt = (unsigned int*)(sums + 3);

    const float NN = (float)N * (float)N;
    const float cT = NN / (2.0f * sums[0]);   // 1/mean (full mean = 2*Sum_{i<j}/N^2)
    const float cS = NN / (2.0f * sums[1]);

    // maskless: below-diagonal and diagonal slab entries are exactly 0 for both mats
    const int v = blockIdx.x * 256 + threadIdx.x;     // 65536 threads = N*N/4 float4s
    float4 tq = ((const float4*)Pp)[v];
    float4 sq = ((const float4*)(Pp + (size_t)N * N))[v];
    float local = fabsf(tq.x * cT - sq.x * cS) + fabsf(tq.y * cT - sq.y * cS)
                + fabsf(tq.z * cT - sq.z * cS) + fabsf(tq.w * cT - sq.w * cS);

    #pragma unroll
    for (int off = 32; off > 0; off >>= 1) local += __shfl_down(local, off, 64);
    __shared__ float wpart[4];
    if ((threadIdx.x & 63) == 0) wpart[threadIdx.x >> 6] = local;
    __syncthreads();

    if (threadIdx.x == 0) {
        atomicAdd(fin, wpart[0] + wpart[1] + wpart[2] + wpart[3]);
        __threadfence();
        unsigned int old = atomicAdd(cnt, 1u);
        if (old == gridDim.x - 1) {                    // last block: all adds visible
            float tot = atomicAdd(fin, 0.0f);          // atomic read of the total
            out[0] = 2.0f * tot;                       // upper-tri counted twice
        }
    }
}

extern "C" void kernel_launch(void* const* d_in, const int* in_sizes, int n_in,
                              void* d_out, int out_size, void* d_ws, size_t ws_size,
                              hipStream_t stream) {
    const float* teacher = (const float*)d_in[0];
    const float* student = (const float*)d_in[1];
    float* out  = (float*)d_out;
    float* Pp   = (float*)d_ws;                 // [2][N*N] f32 slab
    float* sums = Pp + 2 * (size_t)N * N;       // sums[2], fin, cnt

    // one memset node zeroes slab + all scalars
    hipMemsetAsync(d_ws, 0, ZONE_FLOATS * sizeof(float), stream);

    dim3 grid(NTILES, NSLICE, 2);
    pair_sums_kernel<<<grid, 256, 0, stream>>>(teacher, student, Pp, sums);
    final_kernel<<<N * N / 4 / 256, 256, 0, stream>>>(Pp, sums, out);
}

// Round 6
// 93.113 us; speedup vs baseline: 2.3845x; 2.3845x over previous
//
#include <hip/hip_runtime.h>

#define N 512
#define D 512
#define TILE 64        // 64x64 pair tile, 4x4 per thread -> 32:1 VALU:LDS-inst
#define DC 64          // d-slice per block (one LDS stage, one barrier)
#define PITCH 68       // 68%32=4 -> worst 2-way bank alias (free); 16B aligned
#define NT 8           // N/TILE
#define NTILES 36      // upper-triangular tiles
#define NSLICE 8       // D/DC; per-slice private slabs, plain stores (NO atomics)

__device__ __forceinline__ void sl1(float& acc, float x, float y) {
    // 2*SmoothL1(d) = m*(2|d|-m), m=min(|d|,1); 0.5 applied in epilogue.
    float d  = x - y;
    float ad = fabsf(d);
    float m  = fminf(ad, 1.0f);
    acc = fmaf(m, fmaf(2.0f, ad, -m), acc);
}

// ws layout:
//   Pp[2][NSLICE][N*N] f32 slice slabs (16 MB), plain stores, holes masked in final
//   sums[2], fin, cnt scalars (16 B memset)

__global__ __launch_bounds__(256, 4) void pair_sums_kernel(
    const float* __restrict__ Tm, const float* __restrict__ Sm,
    float* __restrict__ Pp, float* __restrict__ sums)
{
    const int mat = blockIdx.z;
    const int sl  = blockIdx.y;
    const float* __restrict__ X = mat ? Sm : Tm;
    float* __restrict__ Pm = Pp + (size_t)(mat * NSLICE + sl) * (N * N);

    // triangular tile decode -> (ti, tj), ti <= tj
    int rem = blockIdx.x, ti = 0;
    while (rem >= NT - ti) { rem -= NT - ti; ++ti; }
    const int tj = ti + rem;
    const int i0 = ti * TILE, j0 = tj * TILE;
    const int d0 = sl * DC;

    __shared__ float Xi[TILE][PITCH];
    __shared__ float Xj[TILE][PITCH];

    const int t  = threadIdx.x;
    const int tx = t & 15;
    const int ty = t >> 4;

    // stage 64 rows x 64 floats per array: 1024 float4 each, 4 per thread
    #pragma unroll
    for (int kk = 0; kk < 4; ++kk) {
        int idx = t + kk * 256;
        int row = idx >> 4;              // 16 float4 per row
        int c4  = (idx & 15) * 4;
        *(float4*)&Xi[row][c4] = *(const float4*)&X[(size_t)(i0 + row) * D + d0 + c4];
        *(float4*)&Xj[row][c4] = *(const float4*)&X[(size_t)(j0 + row) * D + d0 + c4];
    }
    __syncthreads();   // the only barrier before the epilogue

    float acc[4][4];
    #pragma unroll
    for (int m = 0; m < 4; ++m)
        #pragma unroll
        for (int n = 0; n < 4; ++n) acc[m][n] = 0.f;

    #pragma unroll 4
    for (int d4 = 0; d4 < DC / 4; ++d4) {
        float4 p[4], q[4];
        #pragma unroll
        for (int m = 0; m < 4; ++m) p[m] = *(const float4*)&Xi[ty + 16 * m][d4 * 4];
        #pragma unroll
        for (int n = 0; n < 4; ++n) q[n] = *(const float4*)&Xj[tx + 16 * n][d4 * 4];
        #pragma unroll
        for (int m = 0; m < 4; ++m)
            #pragma unroll
            for (int n = 0; n < 4; ++n) {
                sl1(acc[m][n], p[m].x, q[n].x);
                sl1(acc[m][n], p[m].y, q[n].y);
                sl1(acc[m][n], p[m].z, q[n].z);
                sl1(acc[m][n], p[m].w, q[n].w);
            }
    }

    // plain full-tile stores (below-diagonal garbage masked exactly in final);
    // mask only the scalar sum contribution
    const bool diag = (ti == tj);
    float bs = 0.f;
    #pragma unroll
    for (int m = 0; m < 4; ++m)
        #pragma unroll
        for (int n = 0; n < 4; ++n) {
            const int li = ty + 16 * m, lj = tx + 16 * n;
            const float s = 0.5f * acc[m][n];
            Pm[(i0 + li) * N + (j0 + lj)] = s;
            if (!diag || (li <= lj)) bs += s;
        }

    #pragma unroll
    for (int off = 32; off > 0; off >>= 1) bs += __shfl_down(bs, off, 64);
    __shared__ float wpart[4];
    if ((t & 63) == 0) wpart[t >> 6] = bs;
    __syncthreads();
    if (t == 0) atomicAdd(&sums[mat], wpart[0] + wpart[1] + wpart[2] + wpart[3]);
}

__global__ __launch_bounds__(256) void final_kernel(
    const float* __restrict__ Pp, float* __restrict__ sums, float* __restrict__ out)
{
    float* fin = sums + 2;
    unsigned int* cnt = (unsigned int*)(sums + 3);

    const float NN = (float)N * (float)N;
    const float cT = NN / (2.0f * sums[0]);   // 1/mean (full mean = 2*Sum_{i<j}/N^2)
    const float cS = NN / (2.0f * sums[1]);

    const int v  = blockIdx.x * 256 + threadIdx.x;   // 65536 threads = N*N/4 float4s
    const int i  = v >> 7;            // (v*4) / 512
    const int jb = (v & 127) * 4;     // (v*4) % 512

    float local = 0.0f;
    if (jb + 3 >= i) {                // skip float4s fully below the diagonal
        float4 tq = make_float4(0.f, 0.f, 0.f, 0.f);
        float4 sq = make_float4(0.f, 0.f, 0.f, 0.f);
        #pragma unroll
        for (int s = 0; s < NSLICE; ++s) {
            float4 a = ((const float4*)(Pp + (size_t)s * (N * N)))[v];
            float4 b = ((const float4*)(Pp + (size_t)(NSLICE + s) * (N * N)))[v];
            tq.x += a.x; tq.y += a.y; tq.z += a.z; tq.w += a.w;
            sq.x += b.x; sq.y += b.y; sq.z += b.z; sq.w += b.w;
        }
        // exact per-element mask excludes unwritten (poisoned) below-diagonal slots
        if (jb + 0 >= i) local += fabsf(tq.x * cT - sq.x * cS);
        if (jb + 1 >= i) local += fabsf(tq.y * cT - sq.y * cS);
        if (jb + 2 >= i) local += fabsf(tq.z * cT - sq.z * cS);
        if (jb + 3 >= i) local += fabsf(tq.w * cT - sq.w * cS);
    }

    #pragma unroll
    for (int off = 32; off > 0; off >>= 1) local += __shfl_down(local, off, 64);
    __shared__ float wpart[4];
    if ((threadIdx.x & 63) == 0) wpart[threadIdx.x >> 6] = local;
    __syncthreads();

    if (threadIdx.x == 0) {
        atomicAdd(fin, wpart[0] + wpart[1] + wpart[2] + wpart[3]);
        __threadfence();
        unsigned int old = atomicAdd(cnt, 1u);
        if (old == gridDim.x - 1) {              // last block: all adds visible
            float tot = atomicAdd(fin, 0.0f);    // atomic read of the total
            out[0] = 2.0f * tot;                 // upper-tri counted twice
        }
    }
}

extern "C" void kernel_launch(void* const* d_in, const int* in_sizes, int n_in,
                              void* d_out, int out_size, void* d_ws, size_t ws_size,
                              hipStream_t stream) {
    const float* teacher = (const float*)d_in[0];
    const float* student = (const float*)d_in[1];
    float* out  = (float*)d_out;
    float* Pp   = (float*)d_ws;                         // [2][NSLICE][N*N] = 16 MB
    float* sums = Pp + (size_t)2 * NSLICE * N * N;      // sums[2], fin, cnt

    // zero only the 4 accumulated scalars (slab holes are masked, not zeroed)
    hipMemsetAsync(sums, 0, 4 * sizeof(float), stream);

    dim3 grid(NTILES, NSLICE, 2);
    pair_sums_kernel<<<grid, 256, 0, stream>>>(teacher, student, Pp, sums);
    final_kernel<<<N * N / 4 / 256, 256, 0, stream>>>(Pp, sums, out);
}

// Round 7
// 86.173 us; speedup vs baseline: 2.5765x; 1.0805x over previous
//
#include <hip/hip_runtime.h>

#define N 512
#define D 512
#define TILE 32        // pair tile per block: 32x32
#define DCB 128        // d-range per block = 4 warps x 32 dims
#define P4 33          // LDS pitch in float4 (=132 floats, ==4 mod 8 -> octet reads conflict-free)
#define NT 16          // N/TILE
#define NTILES 136     // NT*(NT+1)/2 upper-triangular tiles
#define NSLICE 4       // D/DCB -> slab [2][4][N*N] = 8 MB

__device__ __forceinline__ void sl1(float& acc, float x, float y) {
    // 2*SmoothL1(d) = m*(2|d|-m), m=min(|d|,1); 0.5 applied in epilogue.
    float d  = x - y;
    float ad = fabsf(d);
    float m  = fminf(ad, 1.0f);
    acc = fmaf(m, fmaf(2.0f, ad, -m), acc);
}

__global__ __launch_bounds__(256, 4) void pair_sums_kernel(
    const float* __restrict__ Tm, const float* __restrict__ Sm,
    float* __restrict__ Pp, float* __restrict__ sums)
{
    const int mat = blockIdx.z;
    const int sl  = blockIdx.y;
    const float* __restrict__ X = mat ? Sm : Tm;
    float* __restrict__ Pm = Pp + (size_t)(mat * NSLICE + sl) * (N * N);

    // triangular tile decode -> (ti, tj), ti <= tj
    int rem = blockIdx.x, ti = 0;
    while (rem >= NT - ti) { rem -= NT - ti; ++ti; }
    const int tj = ti + rem;
    const int i0 = ti * TILE, j0 = tj * TILE, d0 = sl * DCB;

    __shared__ float4 Xi4[TILE * P4];
    __shared__ float4 Xj4[TILE * P4];

    const int t  = threadIdx.x;
    const int w  = t >> 6;        // warp id = d-slice of 32 dims
    const int l  = t & 63;
    const int rg = l >> 3;        // 0..7
    const int cg = l & 7;         // 0..7

    // stage 32 rows x 128 floats per array (1024 float4 each, 4 per thread)
    #pragma unroll
    for (int kk = 0; kk < 4; ++kk) {
        int idx = t + kk * 256;
        int row = idx >> 5;              // 32 float4 per row
        int c4  = idx & 31;
        Xi4[row * P4 + c4] = *(const float4*)&X[(size_t)(i0 + row) * D + d0 + c4 * 4];
        Xj4[row * P4 + c4] = *(const float4*)&X[(size_t)(j0 + row) * D + d0 + c4 * 4];
    }
    __syncthreads();

    // each lane: rows {rg,rg+8,rg+16,rg+24} x cols {cg,cg+8,cg+16,cg+24}
    float acc[4][4] = {};
    #pragma unroll 2
    for (int d4 = 0; d4 < 8; ++d4) {     // warp's 32 dims as 8 float4 steps
        const int c = w * 8 + d4;
        float4 p[4], q[4];
        #pragma unroll
        for (int m = 0; m < 4; ++m) p[m] = Xi4[(rg + 8 * m) * P4 + c];
        #pragma unroll
        for (int n = 0; n < 4; ++n) q[n] = Xj4[(cg + 8 * n) * P4 + c];
        #pragma unroll
        for (int m = 0; m < 4; ++m)
            #pragma unroll
            for (int n = 0; n < 4; ++n) {
                sl1(acc[m][n], p[m].x, q[n].x);
                sl1(acc[m][n], p[m].y, q[n].y);
                sl1(acc[m][n], p[m].z, q[n].z);
                sl1(acc[m][n], p[m].w, q[n].w);
            }
    }

    // cross-warp reduction of the 4 d-slice partials (zone reuses Xi4; pitch 17 -> 2-way max)
    __syncthreads();
    float* zone = (float*)Xi4;
    if (w) {
        const int base = ((w - 1) * 64 + l) * 17;
        #pragma unroll
        for (int m = 0; m < 4; ++m)
            #pragma unroll
            for (int n = 0; n < 4; ++n) zone[base + m * 4 + n] = acc[m][n];
    }
    __syncthreads();

    if (w == 0) {
        #pragma unroll
        for (int ww = 0; ww < 3; ++ww) {
            const int base = (ww * 64 + l) * 17;
            #pragma unroll
            for (int m = 0; m < 4; ++m)
                #pragma unroll
                for (int n = 0; n < 4; ++n) acc[m][n] += zone[base + m * 4 + n];
        }
        const bool diag = (ti == tj);
        float bs = 0.f;
        #pragma unroll
        for (int m = 0; m < 4; ++m)
            #pragma unroll
            for (int n = 0; n < 4; ++n) {
                const int li = rg + 8 * m, lj = cg + 8 * n;
                const float s = 0.5f * acc[m][n];
                Pm[(i0 + li) * N + (j0 + lj)] = s;      // full tile; holes masked in final
                if (!diag || (li <= lj)) bs += s;       // count each upper pair once
            }
        #pragma unroll
        for (int off = 32; off > 0; off >>= 1) bs += __shfl_down(bs, off, 64);
        if (l == 0) atomicAdd(&sums[mat], bs);
    }
}

__global__ __launch_bounds__(256) void final_kernel(
    const float* __restrict__ Pp, float* __restrict__ sums, float* __restrict__ out)
{
    float* fin = sums + 2;
    unsigned int* cnt = (unsigned int*)(sums + 3);

    const float NN = (float)N * (float)N;
    const float cT = NN / (2.0f * sums[0]);   // 1/mean (full mean = 2*Sum_{i<j}/N^2)
    const float cS = NN / (2.0f * sums[1]);

    const int v  = blockIdx.x * 256 + threadIdx.x;   // 65536 threads = N*N/4 float4s
    const int i  = v >> 7;            // (v*4) / 512
    const int jb = (v & 127) * 4;     // (v*4) % 512

    float local = 0.0f;
    if (jb + 3 >= i) {                // skip float4s fully below the diagonal
        float4 tq = make_float4(0.f, 0.f, 0.f, 0.f);
        float4 sq = make_float4(0.f, 0.f, 0.f, 0.f);
        #pragma unroll
        for (int s = 0; s < NSLICE; ++s) {
            float4 a = ((const float4*)(Pp + (size_t)s * (N * N)))[v];
            float4 b = ((const float4*)(Pp + (size_t)(NSLICE + s) * (N * N)))[v];
            tq.x += a.x; tq.y += a.y; tq.z += a.z; tq.w += a.w;
            sq.x += b.x; sq.y += b.y; sq.z += b.z; sq.w += b.w;
        }
        // exact per-element mask excludes unwritten (poisoned) below-diagonal slots
        if (jb + 0 >= i) local += fabsf(tq.x * cT - sq.x * cS);
        if (jb + 1 >= i) local += fabsf(tq.y * cT - sq.y * cS);
        if (jb + 2 >= i) local += fabsf(tq.z * cT - sq.z * cS);
        if (jb + 3 >= i) local += fabsf(tq.w * cT - sq.w * cS);
    }

    #pragma unroll
    for (int off = 32; off > 0; off >>= 1) local += __shfl_down(local, off, 64);
    __shared__ float wpart[4];
    if ((threadIdx.x & 63) == 0) wpart[threadIdx.x >> 6] = local;
    __syncthreads();

    if (threadIdx.x == 0) {
        atomicAdd(fin, wpart[0] + wpart[1] + wpart[2] + wpart[3]);
        __threadfence();
        unsigned int old = atomicAdd(cnt, 1u);
        if (old == gridDim.x - 1) {              // last block: all adds visible
            float tot = atomicAdd(fin, 0.0f);    // atomic read of the total
            out[0] = 2.0f * tot;                 // upper-tri counted twice
        }
    }
}

extern "C" void kernel_launch(void* const* d_in, const int* in_sizes, int n_in,
                              void* d_out, int out_size, void* d_ws, size_t ws_size,
                              hipStream_t stream) {
    const float* teacher = (const float*)d_in[0];
    const float* student = (const float*)d_in[1];
    float* out  = (float*)d_out;
    float* Pp   = (float*)d_ws;                         // [2][NSLICE][N*N] = 8 MB
    float* sums = Pp + (size_t)2 * NSLICE * N * N;      // sums[2], fin, cnt

    // zero only the 4 accumulated scalars
    hipMemsetAsync(sums, 0, 4 * sizeof(float), stream);

    dim3 grid(NTILES, NSLICE, 2);
    pair_sums_kernel<<<grid, 256, 0, stream>>>(teacher, student, Pp, sums);
    final_kernel<<<N * N / 4 / 256, 256, 0, stream>>>(Pp, sums, out);
}